// Round 5
// baseline (385.704 us; speedup 1.0000x reference)
//
#include <hip/hip_runtime.h>
#include <hip/hip_bf16.h>
#include <stdint.h>

#define NB 32
#define NS 2048
#define NH 1024

typedef __attribute__((ext_vector_type(8))) unsigned short ushort8v;
typedef __attribute__((ext_vector_type(8))) __bf16 bf16x8;
typedef __attribute__((ext_vector_type(4))) float floatx4;

__device__ __forceinline__ unsigned short f2bf(float f) {
    union { float f; unsigned int u; } x; x.f = f;
    unsigned int r = x.u + 0x7fffu + ((x.u >> 16) & 1u);
    return (unsigned short)(r >> 16);
}
__device__ __forceinline__ float tanh_fast(float x) {
    float e2 = __expf(2.0f * x);
    return 1.0f - 2.0f * __builtin_amdgcn_rcpf(e2 + 1.0f);
}

// ---------- Kernel W: pack Wh (f32 [k][n]) -> WhP bf16 16n x 32k blocks -----
// WhP elem (n,k) at: (n>>4)*16384 + (k>>5)*512 + (n&15)*32 + (k&31)
__global__ void convw_kernel(const float* __restrict__ Wh,
                             unsigned short* __restrict__ WhP)
{
    int kb = blockIdx.x;                  // 128 blocks x 8 k-rows
    int t  = threadIdx.x;                 // 256
    int n  = t * 4;
    int ni = n & 15, nh = n >> 4;
    for (int i = 0; i < 8; ++i) {
        int k = kb * 8 + i;
        float4 w = *(const float4*)(Wh + (size_t)k * NH + n);
        size_t base = (size_t)nh * 16384 + (size_t)(k >> 5) * 512 + (k & 31);
        WhP[base + (size_t)(ni + 0) * 32] = f2bf(w.x);
        WhP[base + (size_t)(ni + 1) * 32] = f2bf(w.y);
        WhP[base + (size_t)(ni + 2) * 32] = f2bf(w.z);
        WhP[base + (size_t)(ni + 3) * 32] = f2bf(w.w);
    }
}

// ---------- Kernel A: proj_s = q @ Ws, tiled over d (f32) -------------------
__global__ void projs_kernel(const float* __restrict__ q,
                             const float* __restrict__ Ws,
                             float* __restrict__ projs)
{
    int b  = blockIdx.x;                  // 32
    int d0 = blockIdx.y * 256;            // 4 d-chunks
    int t  = threadIdx.x;                 // 256
    int kg = t >> 6;                      // 0..3 k-groups of 256
    int dc = t & 63;                      // 0..63 float4-cols
    const float* qb = q + (size_t)b * NH;
    float4 acc = {0.f, 0.f, 0.f, 0.f};
    for (int k = kg * 256; k < kg * 256 + 256; ++k) {
        float qv = qb[k];
        float4 wv = *(const float4*)(Ws + (size_t)k * NH + d0 + dc * 4);
        acc.x += qv * wv.x; acc.y += qv * wv.y;
        acc.z += qv * wv.z; acc.w += qv * wv.w;
    }
    __shared__ float4 red[4][64];
    red[kg][dc] = acc;
    __syncthreads();
    if (t < 64) {
        float4 s = red[0][t];
        float4 s1 = red[1][t], s2 = red[2][t], s3 = red[3][t];
        s.x += s1.x + s2.x + s3.x; s.y += s1.y + s2.y + s3.y;
        s.z += s1.z + s2.z + s3.z; s.w += s1.w + s2.w + s3.w;
        *(float4*)(projs + (size_t)b * NH + d0 + t * 4) = s;
    }
}

// ---------- Kernel B: scores_part[half] = sum_{cols in half} v.tanh(...) ----
// BM=64 rows, BN=512 cols (grid.y half), 8 waves = 2 row-grp x 4 col-grp.
// acc 64 f32/thread. A in LDS (bf16, padded stride 136 shorts, dbuf).
// B streamed from WhP (L2/L1-shared), ring-prefetched.
#define ASTRIDE 136
__global__ __launch_bounds__(512, 2) void scores_kernel(
    const float* __restrict__ E, const unsigned short* __restrict__ WhP,
    const float* __restrict__ projs, const float* __restrict__ v,
    const int* __restrict__ lens, float* __restrict__ spart)
{
    __shared__ __align__(16) unsigned short A2[2][64 * ASTRIDE]; // ~34 KB
    __shared__ float sc[4][64];

    const int tid  = threadIdx.x;
    const int brow = blockIdx.x * 64;
    const int b    = brow >> 11;
    const int sloc = brow & (NS - 1);
    const int half = blockIdx.y;
    const int len  = lens[b];
    if (sloc >= len) return;

    const int wid = tid >> 6;
    const int lane = tid & 63;
    const int l15 = lane & 15;
    const int l16 = lane >> 4;
    const int wr = wid >> 2;              // 0..1 row group (32 rows)
    const int wc = wid & 3;               // 0..3 col group (128 cols)

    floatx4 acc[2][8];
    #pragma unroll
    for (int m = 0; m < 2; ++m)
        #pragma unroll
        for (int c = 0; c < 8; ++c) acc[m][c] = (floatx4){0.f, 0.f, 0.f, 0.f};

    const float* Eb = E + (size_t)brow * NH;
    // staging coords: iter i in {0,1}: e=(i*512+tid)*8, r=e>>7, k0=e&127
    const int sr0 = (tid * 8) >> 7, sk0 = (tid * 8) & 127;
    const int sr1 = ((512 + tid) * 8) >> 7, sk1 = ((512 + tid) * 8) & 127;

    // B frag base (shorts): col-frag (half*32 + wc*8 + c), lane off l15*32+l16*8
    const unsigned short* bbase =
        WhP + (size_t)(half * 32 + wc * 8) * 16384 + l15 * 32 + l16 * 8;
    // A read base row
    const int arow = wr * 32 + l15;       // + m*16

    // ---- prologue: stage chunk 0 ----
    {
        float4 f0 = *(const float4*)(Eb + (size_t)sr0 * NH + sk0);
        float4 f1 = *(const float4*)(Eb + (size_t)sr0 * NH + sk0 + 4);
        float4 f2 = *(const float4*)(Eb + (size_t)sr1 * NH + sk1);
        float4 f3 = *(const float4*)(Eb + (size_t)sr1 * NH + sk1 + 4);
        ushort8v u0, u1;
        u0[0]=f2bf(f0.x); u0[1]=f2bf(f0.y); u0[2]=f2bf(f0.z); u0[3]=f2bf(f0.w);
        u0[4]=f2bf(f1.x); u0[5]=f2bf(f1.y); u0[6]=f2bf(f1.z); u0[7]=f2bf(f1.w);
        u1[0]=f2bf(f2.x); u1[1]=f2bf(f2.y); u1[2]=f2bf(f2.z); u1[3]=f2bf(f2.w);
        u1[4]=f2bf(f3.x); u1[5]=f2bf(f3.y); u1[6]=f2bf(f3.z); u1[7]=f2bf(f3.w);
        *(ushort8v*)&A2[0][sr0 * ASTRIDE + sk0] = u0;
        *(ushort8v*)&A2[0][sr1 * ASTRIDE + sk1] = u1;
    }

    ushort8v br[2][8];
    bf16x8 a[2][2];

    for (int kc = 0; kc < 8; ++kc) {
        const int buf = kc & 1;
        __syncthreads();
        // issue next-chunk global loads early (consumed at end of this chunk)
        float4 f0, f1, f2, f3;
        if (kc < 7) {
            const float* src0 = Eb + (size_t)sr0 * NH + (kc + 1) * 128 + sk0;
            const float* src1 = Eb + (size_t)sr1 * NH + (kc + 1) * 128 + sk1;
            f0 = *(const float4*)src0; f1 = *(const float4*)(src0 + 4);
            f2 = *(const float4*)src1; f3 = *(const float4*)(src1 + 4);
        }
        // preload kk=0 operands
        const unsigned short* bk = bbase + (size_t)(kc * 4) * 512;
        #pragma unroll
        for (int c = 0; c < 8; ++c)
            br[0][c] = *(const ushort8v*)(bk + (size_t)c * 16384);
        #pragma unroll
        for (int m = 0; m < 2; ++m)
            a[0][m] = __builtin_bit_cast(bf16x8, *(const ushort8v*)
                &A2[buf][(arow + m * 16) * ASTRIDE + 0 * 32 + l16 * 8]);

        #pragma unroll
        for (int kk = 0; kk < 4; ++kk) {
            if (kk < 3) {
                const unsigned short* bk2 = bbase + (size_t)(kc * 4 + kk + 1) * 512;
                #pragma unroll
                for (int c = 0; c < 8; ++c)
                    br[(kk + 1) & 1][c] = *(const ushort8v*)(bk2 + (size_t)c * 16384);
                #pragma unroll
                for (int m = 0; m < 2; ++m)
                    a[(kk + 1) & 1][m] = __builtin_bit_cast(bf16x8, *(const ushort8v*)
                        &A2[buf][(arow + m * 16) * ASTRIDE + (kk + 1) * 32 + l16 * 8]);
            }
            #pragma unroll
            for (int m = 0; m < 2; ++m)
                #pragma unroll
                for (int c = 0; c < 8; ++c)
                    acc[m][c] = __builtin_amdgcn_mfma_f32_16x16x32_bf16(
                        a[kk & 1][m], __builtin_bit_cast(bf16x8, br[kk & 1][c]),
                        acc[m][c], 0, 0, 0);
        }
        // convert + write next chunk into other buffer
        if (kc < 7) {
            ushort8v u0, u1;
            u0[0]=f2bf(f0.x); u0[1]=f2bf(f0.y); u0[2]=f2bf(f0.z); u0[3]=f2bf(f0.w);
            u0[4]=f2bf(f1.x); u0[5]=f2bf(f1.y); u0[6]=f2bf(f1.z); u0[7]=f2bf(f1.w);
            u1[0]=f2bf(f2.x); u1[1]=f2bf(f2.y); u1[2]=f2bf(f2.z); u1[3]=f2bf(f2.w);
            u1[4]=f2bf(f3.x); u1[5]=f2bf(f3.y); u1[6]=f2bf(f3.z); u1[7]=f2bf(f3.w);
            *(ushort8v*)&A2[buf ^ 1][sr0 * ASTRIDE + sk0] = u0;
            *(ushort8v*)&A2[buf ^ 1][sr1 * ASTRIDE + sk1] = u1;
        }
    }

    // ---- epilogue: partial score over this half's 512 cols ----
    float psv[8], vv[8];
    #pragma unroll
    for (int c = 0; c < 8; ++c) {
        int col = half * 512 + wc * 128 + c * 16 + l15;
        psv[c] = projs[(size_t)b * NH + col];
        vv[c]  = v[col];
    }
    #pragma unroll
    for (int m = 0; m < 2; ++m) {
        float sp[4] = {0.f, 0.f, 0.f, 0.f};
        #pragma unroll
        for (int c = 0; c < 8; ++c)
            #pragma unroll
            for (int i = 0; i < 4; ++i)
                sp[i] += tanh_fast(acc[m][c][i] + psv[c]) * vv[c];
        #pragma unroll
        for (int i = 0; i < 4; ++i) {
            float s = sp[i];
            s += __shfl_xor(s, 1);
            s += __shfl_xor(s, 2);
            s += __shfl_xor(s, 4);
            s += __shfl_xor(s, 8);
            if (l15 == 0) sc[wc][wr * 32 + m * 16 + l16 * 4 + i] = s;
        }
    }
    __syncthreads();
    if (tid < 64) {
        float s = sc[0][tid] + sc[1][tid] + sc[2][tid] + sc[3][tid];
        spart[(size_t)half * (NB * NS) + brow + tid] = s;
    }
}

// ---------- Kernel C1: masked softmax (sums the two halves) -----------------
__global__ void softmax_kernel(const float* __restrict__ spart,
                               const int* __restrict__ lens,
                               float* __restrict__ wts)
{
    int b = blockIdx.x, tid = threadIdx.x;      // 32 x 256
    int len = lens[b];
    const float* p0 = spart + (size_t)b * NS;
    const float* p1 = spart + (size_t)NB * NS + (size_t)b * NS;
    float loc[8];
    float mx = -3e38f;
    #pragma unroll
    for (int i = 0; i < 8; ++i) {
        int s = tid + i * 256;
        float val = (s < len) ? (p0[s] + p1[s]) : -1e9f;
        loc[i] = val;
        mx = fmaxf(mx, val);
    }
    #pragma unroll
    for (int m = 32; m >= 1; m >>= 1) mx = fmaxf(mx, __shfl_xor(mx, m));
    __shared__ float red[4], red2[4];
    int w = tid >> 6;
    if ((tid & 63) == 0) red[w] = mx;
    __syncthreads();
    mx = fmaxf(fmaxf(red[0], red[1]), fmaxf(red[2], red[3]));
    float sum = 0.f;
    #pragma unroll
    for (int i = 0; i < 8; ++i) { loc[i] = expf(loc[i] - mx); sum += loc[i]; }
    #pragma unroll
    for (int m = 32; m >= 1; m >>= 1) sum += __shfl_xor(sum, m);
    if ((tid & 63) == 0) red2[w] = sum;
    __syncthreads();
    sum = red2[0] + red2[1] + red2[2] + red2[3];
    float inv = 1.f / sum;
    #pragma unroll
    for (int i = 0; i < 8; ++i)
        wts[(size_t)b * NS + tid + i * 256] = loc[i] * inv;
}

// ---------- Kernel C2a: per-chunk partial weighted sums ---------------------
__global__ void attnout1_kernel(const float* __restrict__ E,
                                const float* __restrict__ wts,
                                const int* __restrict__ lens,
                                float* __restrict__ part)
{
    int b  = blockIdx.x;                  // 32
    int ch = blockIdx.y;                  // 16 s-chunks of 128
    int s0 = ch * 128;
    int t  = threadIdx.x;                 // 256
    int len = lens[b];
    float* po = part + ((size_t)ch * NB + b) * NH;
    if (len > 0 && s0 >= len) {           // fully masked chunk (len==0 special)
        *(float4*)(po + t * 4) = (float4){0.f, 0.f, 0.f, 0.f};
        return;
    }
    __shared__ float wsh[128];
    if (t < 128) wsh[t] = wts[(size_t)b * NS + s0 + t];
    __syncthreads();
    int h0 = t * 4;
    const float* Eb = E + ((size_t)b * NS + s0) * NH + h0;
    float4 acc = {0.f, 0.f, 0.f, 0.f};
    for (int s = 0; s < 128; ++s) {
        float w = wsh[s];
        float4 e = *(const float4*)(Eb + (size_t)s * NH);
        acc.x += w * e.x; acc.y += w * e.y;
        acc.z += w * e.z; acc.w += w * e.w;
    }
    *(float4*)(po + h0) = acc;
}

// ---------- Kernel C2b: reduce 16 partials -> out ---------------------------
__global__ void attnout2_kernel(const float* __restrict__ part,
                                float* __restrict__ out)
{
    int b = blockIdx.x, t = threadIdx.x;  // 32 x 256
    float4 acc = {0.f, 0.f, 0.f, 0.f};
    #pragma unroll
    for (int c = 0; c < 16; ++c) {
        float4 p = *(const float4*)(part + ((size_t)c * NB + b) * NH + t * 4);
        acc.x += p.x; acc.y += p.y; acc.z += p.z; acc.w += p.w;
    }
    *(float4*)(out + (size_t)b * NH + t * 4) = acc;
}

// ---------- launch ----------------------------------------------------------
extern "C" void kernel_launch(void* const* d_in, const int* in_sizes, int n_in,
                              void* d_out, int out_size, void* d_ws, size_t ws_size,
                              hipStream_t stream)
{
    const float* q    = (const float*)d_in[0];
    const float* E    = (const float*)d_in[1];
    const int*   lens = (const int*)d_in[2];
    const float* Wh   = (const float*)d_in[3];
    const float* Ws   = (const float*)d_in[4];
    const float* v    = (const float*)d_in[5];
    float* out = (float*)d_out;

    float* ws     = (float*)d_ws;
    float* projs  = ws;                          // 32768
    float* spart  = projs + 32 * 1024;           // 2*65536
    float* wts    = spart + 2 * NB * NS;         // 65536
    float* part   = wts + NB * NS;               // 16*32*1024
    unsigned short* WhP = (unsigned short*)(part + 16 * NB * NH);  // 2 MB

    convw_kernel   <<<128, 256, 0, stream>>>(Wh, WhP);
    projs_kernel   <<<dim3(NB, 4), 256, 0, stream>>>(q, Ws, projs);
    scores_kernel  <<<dim3((NB * NS) / 64, 2), 512, 0, stream>>>(E, WhP, projs, v, lens, spart);
    softmax_kernel <<<NB, 256, 0, stream>>>(spart, lens, wts);
    attnout1_kernel<<<dim3(NB, 16), 256, 0, stream>>>(E, wts, lens, part);
    attnout2_kernel<<<NB, 256, 0, stream>>>(part, out);
}

// Round 6
// 332.933 us; speedup vs baseline: 1.1585x; 1.1585x over previous
//
#include <hip/hip_runtime.h>
#include <hip/hip_bf16.h>
#include <stdint.h>

#define NB 32
#define NS 2048
#define NH 1024

typedef __attribute__((ext_vector_type(8))) unsigned short ushort8v;
typedef __attribute__((ext_vector_type(4))) unsigned short ushort4v;
typedef __attribute__((ext_vector_type(8))) __bf16 bf16x8;
typedef __attribute__((ext_vector_type(4))) float floatx4;

__device__ __forceinline__ unsigned short f2bf(float f) {
    union { float f; unsigned int u; } x; x.f = f;
    unsigned int r = x.u + 0x7fffu + ((x.u >> 16) & 1u);
    return (unsigned short)(r >> 16);
}
__device__ __forceinline__ float tanh_fast(float x) {
    float e2 = __expf(2.0f * x);
    return 1.0f - 2.0f * __builtin_amdgcn_rcpf(e2 + 1.0f);
}
__device__ __forceinline__ void gload_lds16(const void* g, void* l) {
    __builtin_amdgcn_global_load_lds(
        (const __attribute__((address_space(1))) unsigned int*)g,
        (__attribute__((address_space(3))) unsigned int*)l, 16, 0, 0);
}

// ---------- Kernel E: convert E f32 -> Ebf bf16 (valid rows only) -----------
__global__ void conve_kernel(const float* __restrict__ E,
                             const int* __restrict__ lens,
                             unsigned short* __restrict__ Ebf)
{
    int r = blockIdx.x;                   // 65536 rows
    if ((r & (NS - 1)) >= lens[r >> 11]) return;
    int t = threadIdx.x;                  // 256
    float4 f = *(const float4*)(E + (size_t)r * NH + t * 4);
    ushort4v u;
    u[0] = f2bf(f.x); u[1] = f2bf(f.y); u[2] = f2bf(f.z); u[3] = f2bf(f.w);
    *(ushort4v*)(Ebf + (size_t)r * NH + t * 4) = u;
}

// ---------- Kernel W: pack Wh (f32 [k][n]) -> WhP bf16 16n x 32k blocks -----
// WhP elem (n,k) at: (n>>4)*16384 + (k>>5)*512 + (n&15)*32 + (k&31)
__global__ void convw_kernel(const float* __restrict__ Wh,
                             unsigned short* __restrict__ WhP)
{
    int kb = blockIdx.x;                  // 128 blocks x 8 k-rows
    int t  = threadIdx.x;                 // 256
    int n  = t * 4;
    int ni = n & 15, nh = n >> 4;
    for (int i = 0; i < 8; ++i) {
        int k = kb * 8 + i;
        float4 w = *(const float4*)(Wh + (size_t)k * NH + n);
        size_t base = (size_t)nh * 16384 + (size_t)(k >> 5) * 512 + (k & 31);
        WhP[base + (size_t)(ni + 0) * 32] = f2bf(w.x);
        WhP[base + (size_t)(ni + 1) * 32] = f2bf(w.y);
        WhP[base + (size_t)(ni + 2) * 32] = f2bf(w.z);
        WhP[base + (size_t)(ni + 3) * 32] = f2bf(w.w);
    }
}

// ---------- Kernel A: proj_s = q @ Ws, tiled (f32) --------------------------
__global__ void projs_kernel(const float* __restrict__ q,
                             const float* __restrict__ Ws,
                             float* __restrict__ projs)
{
    int b  = blockIdx.x;
    int d0 = blockIdx.y * 256;
    int t  = threadIdx.x;
    int kg = t >> 6;
    int dc = t & 63;
    const float* qb = q + (size_t)b * NH;
    float4 acc = {0.f, 0.f, 0.f, 0.f};
    for (int k = kg * 256; k < kg * 256 + 256; ++k) {
        float qv = qb[k];
        float4 wv = *(const float4*)(Ws + (size_t)k * NH + d0 + dc * 4);
        acc.x += qv * wv.x; acc.y += qv * wv.y;
        acc.z += qv * wv.z; acc.w += qv * wv.w;
    }
    __shared__ float4 red[4][64];
    red[kg][dc] = acc;
    __syncthreads();
    if (t < 64) {
        float4 s = red[0][t];
        float4 s1 = red[1][t], s2 = red[2][t], s3 = red[3][t];
        s.x += s1.x + s2.x + s3.x; s.y += s1.y + s2.y + s3.y;
        s.z += s1.z + s2.z + s3.z; s.w += s1.w + s2.w + s3.w;
        *(float4*)(projs + (size_t)b * NH + d0 + t * 4) = s;
    }
}

// ---------- Kernel B: m97-style 128x128 GEMM + tanh.v epilogue --------------
// BM=128 rows, BN=128 cols (grid.y = 8 col blocks), BK=64, 256 thr = 4 waves
// (2 row-grp x 2 col-grp), acc 4x4 frags = 64 f32/thread. Double-buffered LDS,
// global_load_lds dwordx4 staging for A (Ebf) and B (WhP packed 1KB units).
__global__ __launch_bounds__(256) void scores_kernel(
    const unsigned short* __restrict__ Ebf, const unsigned short* __restrict__ WhP,
    const float* __restrict__ projs, const float* __restrict__ v,
    const int* __restrict__ lens, float* __restrict__ spart)
{
    __shared__ __align__(16) unsigned short Al[2][8192]; // [128][64] bf16 x2
    __shared__ __align__(16) unsigned short Bl[2][8192]; // 16 x 1KB units  x2
    __shared__ float sc[2][2][64];

    const int tid  = threadIdx.x;
    const int brow = blockIdx.x * 128;
    const int b    = brow >> 11;
    const int sloc = brow & (NS - 1);
    const int cb   = blockIdx.y;          // 0..7: cols [cb*128, +128)
    if (sloc >= lens[b]) return;

    const int wave = tid >> 6;
    const int lane = tid & 63;
    const int l15 = lane & 15;
    const int l16 = lane >> 4;
    const int wr = wave >> 1;             // row grp: rows wr*64..+64
    const int wc = wave & 1;              // col grp: cols wc*64..+64

    floatx4 acc[4][4];
    #pragma unroll
    for (int m = 0; m < 4; ++m)
        #pragma unroll
        for (int c = 0; c < 4; ++c) acc[m][c] = (floatx4){0.f, 0.f, 0.f, 0.f};

    // per-lane global source offsets (constant parts)
    const unsigned short* Ea = Ebf + (size_t)(brow + (lane >> 3)) * NH + (lane & 7) * 8;
    const unsigned short* Ba = WhP + (size_t)cb * 8 * 16384 + lane * 8;

    // stage chunk kc into buffer buf: 4 A-loads + 4 B-loads per wave
    #define STAGE(buf, kc)                                                      \
    {                                                                           \
        _Pragma("unroll")                                                       \
        for (int u = 0; u < 4; ++u) {                                           \
            int j = wave * 4 + u;                                               \
            gload_lds16(Ea + (size_t)(j * 8) * NH + (kc) * 64,                  \
                        (void*)&Al[buf][j * 512]);                              \
            gload_lds16(Ba + (size_t)(j >> 1) * 16384 + ((kc) * 2 + (j & 1)) * 512, \
                        (void*)&Bl[buf][j * 512]);                              \
        }                                                                       \
    }

    STAGE(0, 0);
    __syncthreads();

    for (int kc = 0; kc < 16; ++kc) {
        const int buf = kc & 1;
        if (kc < 15) STAGE(buf ^ 1, kc + 1);
        #pragma unroll
        for (int kk = 0; kk < 2; ++kk) {
            bf16x8 a[4], bfr[4];
            #pragma unroll
            for (int m = 0; m < 4; ++m)
                a[m] = __builtin_bit_cast(bf16x8, *(const ushort8v*)
                    &Al[buf][(wr * 64 + m * 16 + l15) * 64 + kk * 32 + l16 * 8]);
            #pragma unroll
            for (int c = 0; c < 4; ++c)
                bfr[c] = __builtin_bit_cast(bf16x8, *(const ushort8v*)
                    &Bl[buf][((wc * 4 + c) * 2 + kk) * 512 + l15 * 32 + l16 * 8]);
            #pragma unroll
            for (int m = 0; m < 4; ++m)
                #pragma unroll
                for (int c = 0; c < 4; ++c)
                    acc[m][c] = __builtin_amdgcn_mfma_f32_16x16x32_bf16(
                        a[m], bfr[c], acc[m][c], 0, 0, 0);
        }
        __syncthreads();
    }

    // epilogue: spart[cb][row] = sum_{cols in this block} v[col]*tanh(acc+ps)
    float psv[4], vv[4];
    #pragma unroll
    for (int c = 0; c < 4; ++c) {
        int col = cb * 128 + wc * 64 + c * 16 + l15;
        psv[c] = projs[(size_t)b * NH + col];
        vv[c]  = v[col];
    }
    #pragma unroll
    for (int m = 0; m < 4; ++m) {
        float sp[4] = {0.f, 0.f, 0.f, 0.f};
        #pragma unroll
        for (int c = 0; c < 4; ++c)
            #pragma unroll
            for (int i = 0; i < 4; ++i)
                sp[i] += tanh_fast(acc[m][c][i] + psv[c]) * vv[c];
        #pragma unroll
        for (int i = 0; i < 4; ++i) {
            float s = sp[i];
            s += __shfl_xor(s, 1);
            s += __shfl_xor(s, 2);
            s += __shfl_xor(s, 4);
            s += __shfl_xor(s, 8);
            if (l15 == 0) sc[wc][wr][m * 16 + l16 * 4 + i] = s;
        }
    }
    __syncthreads();
    if (tid < 128) {
        float s = sc[0][tid >> 6][tid & 63] + sc[1][tid >> 6][tid & 63];
        spart[(size_t)cb * (NB * NS) + brow + tid] = s;
    }
    #undef STAGE
}

// ---------- Kernel C1: masked softmax (sums 8 column partials) --------------
__global__ void softmax_kernel(const float* __restrict__ spart,
                               const int* __restrict__ lens,
                               float* __restrict__ wts)
{
    int b = blockIdx.x, tid = threadIdx.x;      // 32 x 256
    int len = lens[b];
    float loc[8];
    float mx = -3e38f;
    #pragma unroll
    for (int i = 0; i < 8; ++i) {
        int s = tid + i * 256;
        float val = -1e9f;
        if (s < len) {
            val = 0.f;
            #pragma unroll
            for (int c = 0; c < 8; ++c)
                val += spart[(size_t)c * (NB * NS) + (size_t)b * NS + s];
        }
        loc[i] = val;
        mx = fmaxf(mx, val);
    }
    #pragma unroll
    for (int m = 32; m >= 1; m >>= 1) mx = fmaxf(mx, __shfl_xor(mx, m));
    __shared__ float red[4], red2[4];
    int w = tid >> 6;
    if ((tid & 63) == 0) red[w] = mx;
    __syncthreads();
    mx = fmaxf(fmaxf(red[0], red[1]), fmaxf(red[2], red[3]));
    float sum = 0.f;
    #pragma unroll
    for (int i = 0; i < 8; ++i) { loc[i] = expf(loc[i] - mx); sum += loc[i]; }
    #pragma unroll
    for (int m = 32; m >= 1; m >>= 1) sum += __shfl_xor(sum, m);
    if ((tid & 63) == 0) red2[w] = sum;
    __syncthreads();
    sum = red2[0] + red2[1] + red2[2] + red2[3];
    float inv = 1.f / sum;
    #pragma unroll
    for (int i = 0; i < 8; ++i)
        wts[(size_t)b * NS + tid + i * 256] = loc[i] * inv;
}

// ---------- Kernel C2a: per-chunk partial weighted sums ---------------------
__global__ void attnout1_kernel(const float* __restrict__ E,
                                const float* __restrict__ wts,
                                const int* __restrict__ lens,
                                float* __restrict__ part)
{
    int b  = blockIdx.x;                  // 32
    int ch = blockIdx.y;                  // 16 s-chunks of 128
    int s0 = ch * 128;
    int t  = threadIdx.x;                 // 256
    int len = lens[b];
    float* po = part + ((size_t)ch * NB + b) * NH;
    if (len > 0 && s0 >= len) {
        *(float4*)(po + t * 4) = (float4){0.f, 0.f, 0.f, 0.f};
        return;
    }
    __shared__ float wsh[128];
    if (t < 128) wsh[t] = wts[(size_t)b * NS + s0 + t];
    __syncthreads();
    int h0 = t * 4;
    const float* Eb = E + ((size_t)b * NS + s0) * NH + h0;
    float4 acc = {0.f, 0.f, 0.f, 0.f};
    for (int s = 0; s < 128; ++s) {
        float w = wsh[s];
        float4 e = *(const float4*)(Eb + (size_t)s * NH);
        acc.x += w * e.x; acc.y += w * e.y;
        acc.z += w * e.z; acc.w += w * e.w;
    }
    *(float4*)(po + h0) = acc;
}

// ---------- Kernel C2b: reduce 16 partials -> out ---------------------------
__global__ void attnout2_kernel(const float* __restrict__ part,
                                float* __restrict__ out)
{
    int b = blockIdx.x, t = threadIdx.x;  // 32 x 256
    float4 acc = {0.f, 0.f, 0.f, 0.f};
    #pragma unroll
    for (int c = 0; c < 16; ++c) {
        float4 p = *(const float4*)(part + ((size_t)c * NB + b) * NH + t * 4);
        acc.x += p.x; acc.y += p.y; acc.z += p.z; acc.w += p.w;
    }
    *(float4*)(out + (size_t)b * NH + t * 4) = acc;
}

// ---------- launch ----------------------------------------------------------
extern "C" void kernel_launch(void* const* d_in, const int* in_sizes, int n_in,
                              void* d_out, int out_size, void* d_ws, size_t ws_size,
                              hipStream_t stream)
{
    const float* q    = (const float*)d_in[0];
    const float* E    = (const float*)d_in[1];
    const int*   lens = (const int*)d_in[2];
    const float* Wh   = (const float*)d_in[3];
    const float* Ws   = (const float*)d_in[4];
    const float* v    = (const float*)d_in[5];
    float* out = (float*)d_out;

    float* ws     = (float*)d_ws;
    float* projs  = ws;                          // 32768 f
    float* spart  = projs + 32 * 1024;           // 8*65536 f
    float* wts    = spart + 8 * NB * NS;         // 65536 f
    float* part   = wts + NB * NS;               // 16*32*1024 f
    unsigned short* WhP = (unsigned short*)(part + 16 * NB * NH);   // 2 MB
    unsigned short* Ebf = WhP + 1024 * 1024;                        // 128 MB

    conve_kernel   <<<NB * NS, 256, 0, stream>>>(E, lens, Ebf);
    convw_kernel   <<<128, 256, 0, stream>>>(Wh, WhP);
    projs_kernel   <<<dim3(NB, 4), 256, 0, stream>>>(q, Ws, projs);
    scores_kernel  <<<dim3((NB * NS) / 128, 8), 256, 0, stream>>>(Ebf, WhP, projs, v, lens, spart);
    softmax_kernel <<<NB, 256, 0, stream>>>(spart, lens, wts);
    attnout1_kernel<<<dim3(NB, 16), 256, 0, stream>>>(E, wts, lens, part);
    attnout2_kernel<<<NB, 256, 0, stream>>>(part, out);
}

// Round 7
// 221.440 us; speedup vs baseline: 1.7418x; 1.5035x over previous
//
#include <hip/hip_runtime.h>
#include <hip/hip_bf16.h>
#include <stdint.h>

#define NB 32
#define NS 2048
#define NH 1024

typedef __attribute__((ext_vector_type(8))) unsigned short ushort8v;
typedef __attribute__((ext_vector_type(4))) unsigned short ushort4v;
typedef __attribute__((ext_vector_type(8))) __bf16 bf16x8;
typedef __attribute__((ext_vector_type(4))) float floatx4;

__device__ __forceinline__ unsigned short f2bf(float f) {
    union { float f; unsigned int u; } x; x.f = f;
    unsigned int r = x.u + 0x7fffu + ((x.u >> 16) & 1u);
    return (unsigned short)(r >> 16);
}
__device__ __forceinline__ float tanh_fast(float x) {
    float e2 = __expf(2.0f * x);
    return 1.0f - 2.0f * __builtin_amdgcn_rcpf(e2 + 1.0f);
}
__device__ __forceinline__ void gload_lds16(const void* g, void* l) {
    __builtin_amdgcn_global_load_lds(
        (const __attribute__((address_space(1))) unsigned int*)g,
        (__attribute__((address_space(3))) unsigned int*)l, 16, 0, 0);
}

// ---------- Kernel E: convert E f32 -> Ebf bf16 (valid rows only) -----------
__global__ void conve_kernel(const float* __restrict__ E,
                             const int* __restrict__ lens,
                             unsigned short* __restrict__ Ebf)
{
    int r = blockIdx.x;                   // 65536 rows
    if ((r & (NS - 1)) >= lens[r >> 11]) return;
    int t = threadIdx.x;                  // 256
    float4 f = *(const float4*)(E + (size_t)r * NH + t * 4);
    ushort4v u;
    u[0] = f2bf(f.x); u[1] = f2bf(f.y); u[2] = f2bf(f.z); u[3] = f2bf(f.w);
    *(ushort4v*)(Ebf + (size_t)r * NH + t * 4) = u;
}

// ---------- Kernel W: pack Wh (f32 [k][n]) -> WhP bf16 16n x 32k blocks -----
// WhP elem (n,k) at: (n>>4)*16384 + (k>>5)*512 + (n&15)*32 + (k&31)
__global__ void convw_kernel(const float* __restrict__ Wh,
                             unsigned short* __restrict__ WhP)
{
    int kb = blockIdx.x;                  // 128 blocks x 8 k-rows
    int t  = threadIdx.x;                 // 256
    int n  = t * 4;
    int ni = n & 15, nh = n >> 4;
    for (int i = 0; i < 8; ++i) {
        int k = kb * 8 + i;
        float4 w = *(const float4*)(Wh + (size_t)k * NH + n);
        size_t base = (size_t)nh * 16384 + (size_t)(k >> 5) * 512 + (k & 31);
        WhP[base + (size_t)(ni + 0) * 32] = f2bf(w.x);
        WhP[base + (size_t)(ni + 1) * 32] = f2bf(w.y);
        WhP[base + (size_t)(ni + 2) * 32] = f2bf(w.z);
        WhP[base + (size_t)(ni + 3) * 32] = f2bf(w.w);
    }
}

// ---------- Kernel A: proj_s = q @ Ws, tiled (f32) --------------------------
__global__ void projs_kernel(const float* __restrict__ q,
                             const float* __restrict__ Ws,
                             float* __restrict__ projs)
{
    int b  = blockIdx.x;
    int d0 = blockIdx.y * 256;
    int t  = threadIdx.x;
    int kg = t >> 6;
    int dc = t & 63;
    const float* qb = q + (size_t)b * NH;
    float4 acc = {0.f, 0.f, 0.f, 0.f};
    for (int k = kg * 256; k < kg * 256 + 256; ++k) {
        float qv = qb[k];
        float4 wv = *(const float4*)(Ws + (size_t)k * NH + d0 + dc * 4);
        acc.x += qv * wv.x; acc.y += qv * wv.y;
        acc.z += qv * wv.z; acc.w += qv * wv.w;
    }
    __shared__ float4 red[4][64];
    red[kg][dc] = acc;
    __syncthreads();
    if (t < 64) {
        float4 s = red[0][t];
        float4 s1 = red[1][t], s2 = red[2][t], s3 = red[3][t];
        s.x += s1.x + s2.x + s3.x; s.y += s1.y + s2.y + s3.y;
        s.z += s1.z + s2.z + s3.z; s.w += s1.w + s2.w + s3.w;
        *(float4*)(projs + (size_t)b * NH + d0 + t * 4) = s;
    }
}

// ---------- Kernel B: 128x256 GEMM tile, BK=32, 8 waves, tanh.v epilogue ----
// grid.y = 4 col-blocks of 256. acc 4x4 frags/wave = 64 f32/thread.
// A: Ebf via gload_lds, XOR-swizzled (pre-swizzled global src, linear dest,
// swizzled ds_read -> 2-way = free). B: WhP packed 1KB units (conflict-free).
__global__ __launch_bounds__(512) void scores_kernel(
    const unsigned short* __restrict__ Ebf, const unsigned short* __restrict__ WhP,
    const float* __restrict__ projs, const float* __restrict__ v,
    const int* __restrict__ lens, float* __restrict__ spart)
{
    __shared__ __align__(16) unsigned short Al[2][4096];  // [128 rows][32 sh] x2
    __shared__ __align__(16) unsigned short Bl[2][8192];  // 16 x 1KB units  x2
    __shared__ float sc[4][128];

    const int tid  = threadIdx.x;
    const int brow = blockIdx.x * 128;
    const int b    = brow >> 11;
    const int sloc = brow & (NS - 1);
    const int cb   = blockIdx.y;          // 0..3: cols [cb*256, +256)
    if (sloc >= lens[b]) return;

    const int wave = tid >> 6;            // 0..7
    const int lane = tid & 63;
    const int l15 = lane & 15;
    const int l16 = lane >> 4;
    const int wr = wave >> 2;             // 0..1 row grp (64 rows)
    const int wc = wave & 3;              // 0..3 col grp (64 cols)

    floatx4 acc[4][4];
    #pragma unroll
    for (int m = 0; m < 4; ++m)
        #pragma unroll
        for (int c = 0; c < 4; ++c) acc[m][c] = (floatx4){0.f, 0.f, 0.f, 0.f};

    // A staging: unit=wave covers rows 16*wave..+16. lane -> row 16w+(L>>2),
    // slot L&3; pre-swizzle global slot by ^((L>>3)&3) (= (row>>1)&3).
    const unsigned short* Asrc = Ebf
        + (size_t)(brow + wave * 16 + (lane >> 2)) * NH
        + ((lane & 3) ^ ((lane >> 3) & 3)) * 8;
    // B staging: units wave*2, wave*2+1; contiguous 1KB each.
    const unsigned short* Bsrc0 = WhP + (size_t)(cb * 16 + wave * 2) * 16384 + lane * 8;
    const unsigned short* Bsrc1 = Bsrc0 + 16384;

    #define STAGE(buf, kc)                                                     \
    {                                                                          \
        gload_lds16(Asrc + (size_t)(kc) * 32, (void*)&Al[buf][wave * 512]);    \
        gload_lds16(Bsrc0 + (size_t)(kc) * 512, (void*)&Bl[buf][(wave * 2) * 512]); \
        gload_lds16(Bsrc1 + (size_t)(kc) * 512, (void*)&Bl[buf][(wave * 2 + 1) * 512]); \
    }

    // swizzled A-read slot
    const int aslot = (l16 ^ ((l15 >> 1) & 3)) * 8;

    STAGE(0, 0);
    __syncthreads();

    for (int kc = 0; kc < 32; ++kc) {
        const int buf = kc & 1;
        if (kc < 31) STAGE(buf ^ 1, kc + 1);
        bf16x8 a[4], bfr[4];
        #pragma unroll
        for (int m = 0; m < 4; ++m)
            a[m] = __builtin_bit_cast(bf16x8, *(const ushort8v*)
                &Al[buf][(wr * 64 + m * 16 + l15) * 32 + aslot]);
        #pragma unroll
        for (int c = 0; c < 4; ++c)
            bfr[c] = __builtin_bit_cast(bf16x8, *(const ushort8v*)
                &Bl[buf][(wc * 4 + c) * 512 + l15 * 32 + l16 * 8]);
        #pragma unroll
        for (int m = 0; m < 4; ++m)
            #pragma unroll
            for (int c = 0; c < 4; ++c)
                acc[m][c] = __builtin_amdgcn_mfma_f32_16x16x32_bf16(
                    a[m], bfr[c], acc[m][c], 0, 0, 0);
        __syncthreads();
    }
    #undef STAGE

    // epilogue: partial score over this cb's 256 cols
    float psv[4], vv[4];
    #pragma unroll
    for (int c = 0; c < 4; ++c) {
        int col = cb * 256 + wc * 64 + c * 16 + l15;
        psv[c] = projs[(size_t)b * NH + col];
        vv[c]  = v[col];
    }
    #pragma unroll
    for (int m = 0; m < 4; ++m) {
        float sp[4] = {0.f, 0.f, 0.f, 0.f};
        #pragma unroll
        for (int c = 0; c < 4; ++c)
            #pragma unroll
            for (int i = 0; i < 4; ++i)
                sp[i] += tanh_fast(acc[m][c][i] + psv[c]) * vv[c];
        #pragma unroll
        for (int i = 0; i < 4; ++i) {
            float s = sp[i];
            s += __shfl_xor(s, 1);
            s += __shfl_xor(s, 2);
            s += __shfl_xor(s, 4);
            s += __shfl_xor(s, 8);
            if (l15 == 0) sc[wc][wr * 64 + m * 16 + l16 * 4 + i] = s;
        }
    }
    __syncthreads();
    if (tid < 128) {
        float s = sc[0][tid] + sc[1][tid] + sc[2][tid] + sc[3][tid];
        spart[(size_t)cb * (NB * NS) + brow + tid] = s;
    }
}

// ---------- Kernel C1: masked softmax (sums 4 column partials) --------------
__global__ void softmax_kernel(const float* __restrict__ spart,
                               const int* __restrict__ lens,
                               float* __restrict__ wts)
{
    int b = blockIdx.x, tid = threadIdx.x;      // 32 x 256
    int len = lens[b];
    float loc[8];
    float mx = -3e38f;
    #pragma unroll
    for (int i = 0; i < 8; ++i) {
        int s = tid + i * 256;
        float val = -1e9f;
        if (s < len) {
            val = 0.f;
            #pragma unroll
            for (int c = 0; c < 4; ++c)
                val += spart[(size_t)c * (NB * NS) + (size_t)b * NS + s];
        }
        loc[i] = val;
        mx = fmaxf(mx, val);
    }
    #pragma unroll
    for (int m = 32; m >= 1; m >>= 1) mx = fmaxf(mx, __shfl_xor(mx, m));
    __shared__ float red[4], red2[4];
    int w = tid >> 6;
    if ((tid & 63) == 0) red[w] = mx;
    __syncthreads();
    mx = fmaxf(fmaxf(red[0], red[1]), fmaxf(red[2], red[3]));
    float sum = 0.f;
    #pragma unroll
    for (int i = 0; i < 8; ++i) { loc[i] = expf(loc[i] - mx); sum += loc[i]; }
    #pragma unroll
    for (int m = 32; m >= 1; m >>= 1) sum += __shfl_xor(sum, m);
    if ((tid & 63) == 0) red2[w] = sum;
    __syncthreads();
    sum = red2[0] + red2[1] + red2[2] + red2[3];
    float inv = 1.f / sum;
    #pragma unroll
    for (int i = 0; i < 8; ++i)
        wts[(size_t)b * NS + tid + i * 256] = loc[i] * inv;
}

// ---------- Kernel C2a: per-chunk partial weighted sums ---------------------
__global__ void attnout1_kernel(const float* __restrict__ E,
                                const float* __restrict__ wts,
                                const int* __restrict__ lens,
                                float* __restrict__ part)
{
    int b  = blockIdx.x;                  // 32
    int ch = blockIdx.y;                  // 16 s-chunks of 128
    int s0 = ch * 128;
    int t  = threadIdx.x;                 // 256
    int len = lens[b];
    float* po = part + ((size_t)ch * NB + b) * NH;
    if (len > 0 && s0 >= len) {
        *(float4*)(po + t * 4) = (float4){0.f, 0.f, 0.f, 0.f};
        return;
    }
    __shared__ float wsh[128];
    if (t < 128) wsh[t] = wts[(size_t)b * NS + s0 + t];
    __syncthreads();
    int h0 = t * 4;
    const float* Eb = E + ((size_t)b * NS + s0) * NH + h0;
    float4 acc = {0.f, 0.f, 0.f, 0.f};
    for (int s = 0; s < 128; ++s) {
        float w = wsh[s];
        float4 e = *(const float4*)(Eb + (size_t)s * NH);
        acc.x += w * e.x; acc.y += w * e.y;
        acc.z += w * e.z; acc.w += w * e.w;
    }
    *(float4*)(po + h0) = acc;
}

// ---------- Kernel C2b: reduce 16 partials -> out ---------------------------
__global__ void attnout2_kernel(const float* __restrict__ part,
                                float* __restrict__ out)
{
    int b = blockIdx.x, t = threadIdx.x;  // 32 x 256
    float4 acc = {0.f, 0.f, 0.f, 0.f};
    #pragma unroll
    for (int c = 0; c < 16; ++c) {
        float4 p = *(const float4*)(part + ((size_t)c * NB + b) * NH + t * 4);
        acc.x += p.x; acc.y += p.y; acc.z += p.z; acc.w += p.w;
    }
    *(float4*)(out + (size_t)b * NH + t * 4) = acc;
}

// ---------- launch ----------------------------------------------------------
extern "C" void kernel_launch(void* const* d_in, const int* in_sizes, int n_in,
                              void* d_out, int out_size, void* d_ws, size_t ws_size,
                              hipStream_t stream)
{
    const float* q    = (const float*)d_in[0];
    const float* E    = (const float*)d_in[1];
    const int*   lens = (const int*)d_in[2];
    const float* Wh   = (const float*)d_in[3];
    const float* Ws   = (const float*)d_in[4];
    const float* v    = (const float*)d_in[5];
    float* out = (float*)d_out;

    float* ws     = (float*)d_ws;
    float* projs  = ws;                          // 32768 f
    float* spart  = projs + 32 * 1024;           // 4*65536 f
    float* wts    = spart + 4 * NB * NS;         // 65536 f
    float* part   = wts + NB * NS;               // 16*32*1024 f
    unsigned short* WhP = (unsigned short*)(part + 16 * NB * NH);   // 2 MB
    unsigned short* Ebf = WhP + 1024 * 1024;                        // 128 MB

    conve_kernel   <<<NB * NS, 256, 0, stream>>>(E, lens, Ebf);
    convw_kernel   <<<128, 256, 0, stream>>>(Wh, WhP);
    projs_kernel   <<<dim3(NB, 4), 256, 0, stream>>>(q, Ws, projs);
    scores_kernel  <<<dim3((NB * NS) / 128, 4), 512, 0, stream>>>(Ebf, WhP, projs, v, lens, spart);
    softmax_kernel <<<NB, 256, 0, stream>>>(spart, lens, wts);
    attnout1_kernel<<<dim3(NB, 16), 256, 0, stream>>>(E, wts, lens, part);
    attnout2_kernel<<<NB, 256, 0, stream>>>(part, out);
}